// Round 1
// baseline (570.157 us; speedup 1.0000x reference)
//
#include <hip/hip_runtime.h>

// SoftMSM loss on MI355X.
// Reference: soft Move-Split-Merge DP, T=U=512, B=64, c=1, gamma=1.
//
// Round 0: anti-diagonal wavefront, one block per batch element.
//   - thread j owns column j; i = d - j on diagonal d (d = 0..1022)
//   - 3 rotating LDS diagonal buffers (dm2 = diag d-2, dm1 = diag d-1, dcur)
//   - x / dx / dx^2 staged in LDS (read at index i = d-j: consecutive lanes
//     read consecutive descending addresses -> conflict-free)
//   - y_j, dy = y_j - y_{j-1}, dy^2 are per-thread register constants
//   - match cost (x_i - y_j)^2 doubles as b^2 for BOTH trans() calls
//   - scalar mean via atomicAdd after a zeroing kernel (d_out is poisoned)

#define TT 512
#define UU 512
#define BB 64
#define C_CONSTF 1.0f
#define GATE_EPSF 1e-9f

// softmin2 with gamma=1: -log(exp(-p) + exp(-q)) = min(p,q) - log(1 + exp(-|p-q|))
__device__ __forceinline__ float softmin2_g1(float p, float q) {
  float mn = fminf(p, q);
  float t = __expf(-fabsf(p - q));
  return mn - __logf(1.0f + t);
}

// trans(x_val, y_prev, z_other) with a = x_val - y_prev, b = x_val - z_other
// = c + (1 - g) * softmin2(a^2, b^2),  g = 0.5*(1 - u/sqrt(u^2+eps)), u = a*b
__device__ __forceinline__ float trans_g1(float a, float a2, float b, float b2) {
  float u = a * b;
  float g = 0.5f * (1.0f - u * rsqrtf(__fmaf_rn(u, u, GATE_EPSF)));
  return C_CONSTF + (1.0f - g) * softmin2_g1(a2, b2);
}

__global__ __launch_bounds__(UU) void msm_kernel(const float* __restrict__ x,
                                                 const float* __restrict__ y,
                                                 float* __restrict__ out) {
  const int b = blockIdx.x;
  const int j = threadIdx.x;

  __shared__ float xs[TT];
  __shared__ float dxs[TT];
  __shared__ float dx2s[TT];
  __shared__ float ysh[UU];
  __shared__ float bufA[UU], bufB[UU], bufC[UU];

  const float xv = x[b * TT + j];
  const float yj = y[b * UU + j];
  xs[j] = xv;
  ysh[j] = yj;
  __syncthreads();
  {
    float xm1 = (j >= 1) ? xs[j - 1] : 0.0f;
    float dx = xv - xm1;
    dxs[j] = dx;       // dxs[0] never used (up needs i >= 1)
    dx2s[j] = dx * dx;
  }
  const float yjm1 = (j >= 1) ? ysh[j - 1] : 0.0f;
  const float dy = yj - yjm1;   // dy for j==0 never used (left needs j >= 1)
  const float dy2 = dy * dy;
  __syncthreads();

  float* dm2 = bufA;   // diagonal d-2
  float* dm1 = bufB;   // diagonal d-1
  float* dcur = bufC;  // diagonal d

  for (int d = 0; d < TT + UU - 1; ++d) {
    const int i = d - j;
    if (i >= 0 && i < TT) {
      const float xi = xs[i];
      const float bu = xi - yj;   // up's b = x_i - y_j; left's b = -(bu)
      const float m2 = bu * bu;   // match cost AND b^2 for both trans calls
      float v;
      if (i == 0) {
        if (j == 0) {
          v = m2;  // C[0,0] = (x0 - y0)^2
        } else {
          // C[0,j] = C[0,j-1] + trans(y_j, y_{j-1}, x_0)
          float lf = trans_g1(dy, dy2, -bu, m2);
          v = dm1[j - 1] + lf;
        }
      } else if (j == 0) {
        // C[i,0] = C[i-1,0] + trans(x_i, x_{i-1}, y_0)
        float up = trans_g1(dxs[i], dx2s[i], bu, m2);
        v = dm1[0] + up;
      } else {
        float up = trans_g1(dxs[i], dx2s[i], bu, m2);
        float lf = trans_g1(dy, dy2, -bu, m2);
        float dd = dm2[j - 1] + m2;  // diag:  C[i-1,j-1] + match
        float du = dm1[j] + up;      // up:    C[i-1,j]   + up-cost
        float cl = dm1[j - 1] + lf;  // left:  C[i,j-1]   + left-cost
        // softmin3, gamma=1, min-shifted (one exp arg is exactly 0)
        float mn = fminf(dd, fminf(du, cl));
        float s = __expf(mn - dd) + __expf(mn - du) + __expf(mn - cl);
        v = mn - __logf(s);
      }
      dcur[j] = v;
      if (d == TT + UU - 2) {       // only thread j = UU-1 (i = TT-1) is here
        atomicAdd(out, v * (1.0f / BB));
      }
    }
    __syncthreads();
    float* tmp = dm2; dm2 = dm1; dm1 = dcur; dcur = tmp;
  }
}

__global__ void zero_out_kernel(float* __restrict__ out) { out[0] = 0.0f; }

extern "C" void kernel_launch(void* const* d_in, const int* in_sizes, int n_in,
                              void* d_out, int out_size, void* d_ws, size_t ws_size,
                              hipStream_t stream) {
  const float* x = (const float*)d_in[0];
  const float* y = (const float*)d_in[1];
  float* out = (float*)d_out;
  zero_out_kernel<<<1, 1, 0, stream>>>(out);
  msm_kernel<<<BB, UU, 0, stream>>>(x, y, out);
}

// Round 3
// 315.586 us; speedup vs baseline: 1.8067x; 1.8067x over previous
//
#include <hip/hip_runtime.h>
#include <math.h>

// SoftMSM loss on MI355X — round 2.
// E-space (exp(-cost)) linear DP + hard gate + wave-synchronous pipeline,
// with overflow-PROOF scale bookkeeping (round 1 NaN'd in the rescale path).
//
//   E[i,j] = E[i-1,j-1]*exp(-match) + E[i-1,j]*Wu + E[i,j-1]*Wl   (exact
//   exp-space softmin3, gamma=1);  Wu/Wl = e^{-c} * (gate ? S : 1),
//   S = exp(-a^2)+exp(-b^2).  Hard gate error <= g(u)*|u| <= 1.6e-5/cell
//   since softmin2(a^2,b^2) <= |a*b|.
//
//   One wave per batch element; lane owns 8 columns; lane j runs row s-j at
//   super-step s; boundary E via __shfl_up — zero barriers in the main loop.
//
//   Scaling: E_true = E_stored * 2^kacc per lane. Each step: rebase my state
//   and the incoming boundary to knew = max(kacc, k_in) — every ldexpf shift
//   is <= 0 (overflow impossible; underflow drops negligible path mass).
//   End of row: frexpf/ldexpf normalize so max_k Ep[k] ~ [0.5, 1).

#define TT 512
#define BATCH 64
#define G 8
#define LN2F 0.69314718055994530942f

__global__ __launch_bounds__(64) void msm_wave_kernel(const float* __restrict__ x,
                                                      const float* __restrict__ y,
                                                      float* __restrict__ out) {
  const int b = blockIdx.x;
  const int lane = threadIdx.x;            // 0..63
  const int base = lane * G;               // first owned column

  __shared__ float X[TT], DX[TT], KEDX2[TT];   // KEDX2 = e^{-c} * exp(-dx^2)

  const float Kc = 0.36787944117144233f;   // e^{-c}, c = 1

#pragma unroll
  for (int k = 0; k < G; ++k) X[base + k] = x[b * TT + base + k];
  __syncthreads();
#pragma unroll
  for (int k = 0; k < G; ++k) {
    int i = base + k;
    float xm1 = (i > 0) ? X[i - 1] : 0.0f;
    float dx = X[i] - xm1;                 // DX[0]/KEDX2[0]: row 0 has up=0, harmless
    DX[i] = dx;
    KEDX2[i] = Kc * __expf(-dx * dx);
  }
  float yv[G], dyv[G], kedy2[G];
  {
    float ym1 = (base > 0) ? y[b * TT + base - 1] : 0.0f;
#pragma unroll
    for (int k = 0; k < G; ++k) {
      float yk = y[b * TT + base + k];
      yv[k] = yk;
      float dy = yk - ym1;                 // col 0's dy unused (left input is 0 there)
      dyv[k] = dy;
      kedy2[k] = Kc * __expf(-dy * dy);
      ym1 = yk;
    }
  }
  __syncthreads();

  float Ep[G];                             // previous-row E, lane scale 2^kacc
#pragma unroll
  for (int k = 0; k < G; ++k) Ep[k] = 0.0f;
  float bLc = 0.0f;                        // E[last row done, base+G-1]
  float bLp = 0.0f;                        // E[last row done - 1, base+G-1]
  int kacc = 0;

  const int STEPS = TT + 63;               // 575

  for (int s = 0; s < STEPS; ++s) {
    float bc_in = __shfl_up(bLc, 1);       // E[r,   base-1], scale 2^k_in
    float bp_in = __shfl_up(bLp, 1);       // E[r-1, base-1], scale 2^k_in
    int k_in = __shfl_up(kacc, 1);
    const int r = s - lane;
    if (lane == 0) {
      bc_in = 0.0f;
      bp_in = (r == 0) ? 1.0f : 0.0f;      // seed E[-1,-1] = 1 -> C[0,0] = match
      k_in = kacc;                         // dummy neighbor: same scale, zero values
    }
    if (r >= 0 && r < TT) {
      if (r == 0) kacc = k_in;             // enter pipeline in neighbor's scale
      // rebase to the larger scale: all shifts <= 0 -> no overflow ever
      const int knew = (k_in > kacc) ? k_in : kacc;
      const int dm = kacc - knew;          // <= 0
      const int di = k_in - knew;          // <= 0
      if (dm != 0) {
#pragma unroll
        for (int k = 0; k < G; ++k) Ep[k] = ldexpf(Ep[k], dm);
        bLc = ldexpf(bLc, dm);
        bLp = ldexpf(bLp, dm);
        kacc = knew;
      }
      float diag = ldexpf(bp_in, di);
      float left = ldexpf(bc_in, di);

      const float xr = X[r];
      const float dxr = DX[r];
      const float kex2 = KEDX2[r];
#pragma unroll
      for (int k = 0; k < G; ++k) {
        float bu = xr - yv[k];
        float m2 = bu * bu;
        float Em = __expf(-m2);            // exp(-match), shared 3 ways
        float KEm = Kc * Em;
        float Su = kex2 + KEm;             // Kc*(exp(-dx^2) + exp(-m2))
        float Sl = kedy2[k] + KEm;
        float uu = dxr * bu;               // up gate u = dx*(x-y)
        float ul = dyv[k] * bu;            // left gate u = dy*(y-x) > 0 <=> ul < 0
        float Wu = (uu > 0.0f) ? Su : Kc;
        float Wl = (ul < 0.0f) ? Sl : Kc;
        float up = Ep[k];
        float en = diag * Em + up * Wu + left * Wl;
        diag = up;
        left = en;
        Ep[k] = en;
      }
      bLp = bLc;
      bLc = Ep[G - 1];
      // normalize: max_k Ep[k] -> [0.5, 1)
      float vmax = Ep[0];
#pragma unroll
      for (int k = 1; k < G; ++k) vmax = fmaxf(vmax, Ep[k]);
      int e;
      (void)frexpf(vmax, &e);              // vmax = m*2^e; vmax==0 -> e=0 (skip)
      if (e != 0) {
#pragma unroll
        for (int k = 0; k < G; ++k) Ep[k] = ldexpf(Ep[k], -e);
        bLc = ldexpf(bLc, -e);
        bLp = ldexpf(bLp, -e);
        kacc += e;
      }
    }
  }

  if (lane == 63) {
    // cost = -log(E_true) = -(log(stored) + kacc*ln2)
    float v = -(__logf(bLc) + (float)kacc * LN2F);
    atomicAdd(out, v * (1.0f / BATCH));
  }
}

__global__ void zero_out_kernel(float* __restrict__ out) { out[0] = 0.0f; }

extern "C" void kernel_launch(void* const* d_in, const int* in_sizes, int n_in,
                              void* d_out, int out_size, void* d_ws, size_t ws_size,
                              hipStream_t stream) {
  const float* x = (const float*)d_in[0];
  const float* y = (const float*)d_in[1];
  float* out = (float*)d_out;
  zero_out_kernel<<<1, 1, 0, stream>>>(out);
  msm_wave_kernel<<<BATCH, 64, 0, stream>>>(x, y, out);
}

// Round 4
// 259.765 us; speedup vs baseline: 2.1949x; 1.2149x over previous
//
#include <hip/hip_runtime.h>
#include <math.h>

// SoftMSM loss on MI355X — round 3.
// E-space linear DP (exact softmin3 in exp space) + hard gate + wave pipeline,
// restructured for latency: F-space reparam, phase-split ILP, branchless scaling.
//
//   F[i,j] = e^{c(i+j)} E[i,j]  (c=1):
//     F[i,j] = F[i-1,j-1]*A + F[i-1,j]*B + F[i,j-1]*C
//     A = e^{2-m2},  B = (u_up>0 ? ex2+Em : 1),  C = (u_lf>0 ? edy2+Em : 1)
//     m2=(x_i-y_j)^2, Em=e^{-m2}, ex2=e^{-dx^2}, edy2=e^{-dy^2}
//   cost = 1022 - log(F[511,511])
//
//   One wave per batch; lane owns 8 columns; lane j runs row s-j at step s;
//   boundary F via __shfl_up (no barriers). Per-lane scale 2^kacc, rebased
//   to max(kacc,k_in) each step (shifts <= 0 except the normalize term,
//   bounded <= +125 -> overflow-proof), normalize folded into chain reads.

#define TT 512
#define BATCH 64
#define G 8

#define C1F 1.2011224087864498f    // sqrt(log2 e)
#define C2F 2.8853900817779268f    // 2*log2 e
#define K2F 0.13533528323661270f   // e^-2
#define LN2F 0.69314718055994531f

#if __has_builtin(__builtin_amdgcn_exp2f)
#define EXP2F(x) __builtin_amdgcn_exp2f(x)
#else
#define EXP2F(x) __expf((x) * LN2F)
#endif

__global__ __launch_bounds__(64) void msm_wave_kernel(const float* __restrict__ x,
                                                      const float* __restrict__ y,
                                                      float* __restrict__ out) {
  const int b = blockIdx.x;
  const int lane = threadIdx.x;            // 0..63
  const int base = lane * G;

  __shared__ float XC[TT];                 // x * C1
  __shared__ float DXS[TT];                // dx (sign carrier)
  __shared__ float EX2[TT];                // exp(-dx^2)

  // stage raw x
#pragma unroll
  for (int k = 0; k < G; ++k) XC[base + k] = x[b * TT + base + k];
  __syncthreads();
  float rx[G], rdx[G];
#pragma unroll
  for (int k = 0; k < G; ++k) {
    int i = base + k;
    rx[k] = XC[i];
    float xm1 = (i > 0) ? XC[i - 1] : 0.0f;
    rdx[k] = rx[k] - xm1;                  // row 0's dx unused (Ep=0 there)
  }
  __syncthreads();
#pragma unroll
  for (int k = 0; k < G; ++k) {
    int i = base + k;
    XC[i] = rx[k] * C1F;
    DXS[i] = rdx[k];
    EX2[i] = __expf(-rdx[k] * rdx[k]);
  }

  float yc[G], dyS[G], edy2[G];
  {
    float ym1 = (base > 0) ? y[b * TT + base - 1] : 0.0f;
#pragma unroll
    for (int k = 0; k < G; ++k) {
      float yk = y[b * TT + base + k];
      yc[k] = yk * C1F;
      float dy = yk - ym1;                 // col 0's dy unused (left input 0)
      dyS[k] = dy;
      edy2[k] = __expf(-dy * dy);
      ym1 = yk;
    }
  }
  __syncthreads();

  float Ep[G];
#pragma unroll
  for (int k = 0; k < G; ++k) Ep[k] = 0.0f;
  float bLc = 0.0f;                        // F[row done,   base+G-1] (lane scale)
  float bLp = 0.0f;                        // F[row done-1, base+G-1]
  int kacc = 0;                            // F_true = stored * 2^kacc

  const int STEPS = TT + 63;               // 575

  for (int s = 0; s < STEPS; ++s) {
    float bc_in = __shfl_up(bLc, 1);       // F[r,   base-1], scale 2^k_in
    float bp_in = __shfl_up(bLp, 1);       // F[r-1, base-1]
    int k_in = __shfl_up(kacc, 1);
    const int r = s - lane;
    if (lane == 0) {
      bc_in = 0.0f;
      bp_in = (r == 0) ? K2F : 0.0f;       // seed F[-1,-1] = e^{-2} -> C[0,0]=match
      k_in = kacc;
    }
    if (r >= 0 && r < TT) {
      // --- branchless normalize + rebase ---
      float vmax = fmaxf(fmaxf(fmaxf(Ep[0], Ep[1]), fmaxf(Ep[2], Ep[3])),
                         fmaxf(fmaxf(Ep[4], Ep[5]), fmaxf(Ep[6], Ep[7])));
      unsigned ue = (__float_as_uint(vmax) >> 23) & 0xFFu;
      int e = (ue == 0u) ? 0 : ((int)ue - 126);     // stored*2^-e in [0.5,1)
      int kaccN = kacc + e;
      if (r == 0) kaccN = k_in;                     // pipeline entry (Ep==0, e==0)
      int knew = (kaccN > k_in) ? kaccN : k_in;
      float mEp = ldexpf(1.0f, kaccN - knew - e);   // exponent <= +125, no ovf
      float mIn = ldexpf(1.0f, k_in - knew);        // exponent <= 0
      kacc = knew;
      float diag = bp_in * mIn;
      float left = bc_in * mIn;
      bLc *= mEp;
      bLp *= mEp;

      const float xc = XC[r];
      const float dxr = DXS[r];
      const float ex2 = EX2[r];

      // --- phase 1: weights (independent, overlap shuffle/exp latency) ---
      float Av[G], Bv[G], Cv[G];
#pragma unroll
      for (int k = 0; k < G; ++k) {
        float s1 = xc - yc[k];                       // (x-y)*sqrt(log2e)
        float A = EXP2F(__fmaf_rn(s1, -s1, C2F));    // e^{2-m2}
        float Em = A * K2F;                          // e^{-m2}
        float gu = dxr * s1;                         // sign of dx*(x-y)
        float gl = dyS[k] * s1;                      // <0 <=> dy*(y-x)>0
        Av[k] = A;
        Bv[k] = (gu > 0.0f) ? (ex2 + Em) : 1.0f;
        Cv[k] = (gl < 0.0f) ? (edy2[k] + Em) : 1.0f;
      }
      // --- phase 2: serial chain (8 dependent FMAs) ---
#pragma unroll
      for (int k = 0; k < G; ++k) {
        float up = Ep[k] * mEp;                      // normalize folded in
        float en = __fmaf_rn(left, Cv[k], __fmaf_rn(diag, Av[k], up * Bv[k]));
        diag = up;
        left = en;
        Ep[k] = en;
      }
      bLp = bLc;
      bLc = Ep[G - 1];
    }
  }

  if (lane == 63) {
    // cost = 1022 - log(F_true) = 1022 - (log(stored) + kacc*ln2)
    float v = 1022.0f - (__logf(bLc) + (float)kacc * LN2F);
    atomicAdd(out, v * (1.0f / BATCH));
  }
}

__global__ void zero_out_kernel(float* __restrict__ out) { out[0] = 0.0f; }

extern "C" void kernel_launch(void* const* d_in, const int* in_sizes, int n_in,
                              void* d_out, int out_size, void* d_ws, size_t ws_size,
                              hipStream_t stream) {
  const float* x = (const float*)d_in[0];
  const float* y = (const float*)d_in[1];
  float* out = (float*)d_out;
  zero_out_kernel<<<1, 1, 0, stream>>>(out);
  msm_wave_kernel<<<BATCH, 64, 0, stream>>>(x, y, out);
}